// Round 6
// baseline (306.577 us; speedup 1.0000x reference)
//
#include <hip/hip_runtime.h>
#include <hip/hip_bf16.h>

// ---- problem constants ----
#define DB   2
#define DS   2048
#define DH   2048
#define DNH  32
#define DKVH 8
#define DHD  64
#define DM   4096    // B*S
#define DNQKV 3072   // NH*HD + 2*KVH*HD

typedef __attribute__((ext_vector_type(8))) short bf16x8;
typedef __attribute__((ext_vector_type(4))) float f32x4;
typedef __attribute__((ext_vector_type(8))) unsigned short us8;
typedef __attribute__((ext_vector_type(4))) unsigned short us4;
typedef __attribute__((ext_vector_type(2))) unsigned int u32x2;

__device__ __forceinline__ float b2f(unsigned short u) {
  unsigned int x = ((unsigned int)u) << 16;
  return __builtin_bit_cast(float, x);
}
__device__ __forceinline__ unsigned short f2b(float f) {
  unsigned int u = __builtin_bit_cast(unsigned int, f);
  return (unsigned short)((u + 0x8000u) >> 16);
}
__device__ __forceinline__ unsigned int cvt_pk_bf16(float lo, float hi) {
  unsigned int r;
  asm("v_cvt_pk_bf16_f32 %0, %1, %2" : "=v"(r) : "v"(lo), "v"(hi));
  return r;
}
__device__ __forceinline__ void async_copy16(void* lds, const void* g) {
  __builtin_amdgcn_global_load_lds((const __attribute__((address_space(1))) void*)g,
                                   (__attribute__((address_space(3))) void*)lds,
                                   16, 0, 0);
}

// raw barrier (no waitcnt drain) + compiler memory fences
#define BARRIER() do { asm volatile("" ::: "memory"); __builtin_amdgcn_s_barrier(); asm volatile("" ::: "memory"); } while (0)
#define LGKM0()   asm volatile("s_waitcnt lgkmcnt(0)" ::: "memory")
#define WAITVM(n) asm volatile("s_waitcnt vmcnt(" #n ")" ::: "memory")
#define MFMA16(d, a, bb) (d) = __builtin_amdgcn_mfma_f32_16x16x32_bf16((a), (bb), (d), 0, 0, 0)

// ---- inline dtype detector: wave-reduce over first 256 shorts of Wq ----
__device__ __forceinline__ int detect_inline(const unsigned short* __restrict__ w) {
  int t = threadIdx.x & 63;
  int trips = 0;
#pragma unroll
  for (int i = 0; i < 4; i++) {
    unsigned short u = w[t * 4 + i];
    int e = (u >> 7) & 0xFF;
    if (e >= 161 || (e <= 93 && e != 0)) trips++;
  }
#pragma unroll
  for (int off = 32; off > 0; off >>= 1) trips += __shfl_down(trips, off);
  return __shfl(trips, 0) >= 8;   // 1 = fp32 I/O, 0 = bf16
}

// ============================================================================
// fused preprocessing: one launch. (unchanged, round-5)
// ============================================================================
__global__ __launch_bounds__(256)
void prep(const void* __restrict__ hs, const void* __restrict__ wq,
          const void* __restrict__ wk, const void* __restrict__ wv,
          const void* __restrict__ wo,
          unsigned short* __restrict__ xb, unsigned short* __restrict__ wtqkv,
          unsigned short* __restrict__ wto) {
  __shared__ float tile[32][33];
  int mode = detect_inline((const unsigned short*)wq);
  int bid = blockIdx.x;
  if (bid < 4096) {
    int i = (bid * 256 + threadIdx.x) * 8;
    if (mode) {
      const float* f = (const float*)hs;
      us8 o;
#pragma unroll
      for (int j = 0; j < 8; j++) o[j] = f2b(f[i + j]);
      *(us8*)&xb[i] = o;
    } else {
      *(us8*)&xb[i] = *(const us8*)((const unsigned short*)hs + i);
    }
    return;
  }
  const void* win; unsigned short* out; int C, bx, by;
  if (bid < 8192)       { int l = bid - 4096;  win = wq; out = wtqkv;                         C = 2048; bx = l & 63; by = l >> 6; }
  else if (bid < 9216)  { int l = bid - 8192;  win = wk; out = wtqkv + (size_t)2048 * 2048;   C = 512;  bx = l & 15; by = l >> 4; }
  else if (bid < 10240) { int l = bid - 9216;  win = wv; out = wtqkv + (size_t)2560 * 2048;   C = 512;  bx = l & 15; by = l >> 4; }
  else                  { int l = bid - 10240; win = wo; out = wto;                           C = 2048; bx = l & 63; by = l >> 6; }
  int c0 = bx * 32, r0 = by * 32;
  int tx = threadIdx.x & 31, ty = threadIdx.x >> 5;
  if (mode) {
    const float* f = (const float*)win;
    for (int i = ty; i < 32; i += 8) tile[i][tx] = f[(size_t)(r0 + i) * C + c0 + tx];
  } else {
    const unsigned short* bsrc = (const unsigned short*)win;
    for (int i = ty; i < 32; i += 8) tile[i][tx] = b2f(bsrc[(size_t)(r0 + i) * C + c0 + tx]);
  }
  __syncthreads();
  for (int i = ty; i < 32; i += 8) out[(size_t)(c0 + i) * 2048 + r0 + tx] = f2b(tile[tx][i]);
}

#define QSC 0.18033688011112042f   // (1/8) * log2(e)

// ============================================================================
// 8-phase 256x256 QKV GEMM + RoPE + head-major scatter. (unchanged)
// ============================================================================
__global__ __launch_bounds__(512, 2)
void gemm_qkv(const unsigned short* __restrict__ A, const unsigned short* __restrict__ Bt,
              const int* __restrict__ pos_ids,
              unsigned short* __restrict__ qws, unsigned short* __restrict__ kws,
              unsigned short* __restrict__ vt) {
  __shared__ __align__(16) unsigned short sm[65536];  // 128 KiB
  int tid = threadIdx.x, lane = tid & 63, wave = tid >> 6;
  int wm = wave >> 2, wn = wave & 3;           // 2 x 4 waves, wave tile 128x64
  int quad = lane >> 4, l15 = lane & 15;

  int bid = blockIdx.x;                         // 192 blocks, 192 % 8 == 0
  int wg = (bid & 7) * 24 + (bid >> 3);         // XCD-contiguous chunks of 24
  int ty = wg / 12, tx = wg - ty * 12;
  size_t tm0 = (size_t)ty * 256, tn0 = (size_t)tx * 256;

  const unsigned short* Ab = A + tm0 * 2048;
  const unsigned short* Bb = Bt + tn0 * 2048;

  auto UA = [&](int bu, int kh) { return sm + (bu * 2 + kh) * 8192; };
  auto UB = [&](int bu, int kh) { return sm + 32768 + (bu * 2 + kh) * 8192; };

  int c0 = tid, c1 = tid + 512;
  int r0s = c0 >> 2, r1s = c1 >> 2;
  int cc0 = (c0 & 3) ^ ((r0s >> 1) & 3);
  int cc1 = (c1 & 3) ^ ((r1s >> 1) & 3);
  size_t ga0 = (size_t)r0s * 2048 + cc0 * 8;
  size_t ga1 = (size_t)r1s * 2048 + cc1 * 8;

  auto stA = [&](int t, int kh, int bu) {
    const unsigned short* s = Ab + (size_t)t * 64 + kh * 32;
    async_copy16(UA(bu, kh) + c0 * 8, s + ga0);
    async_copy16(UA(bu, kh) + c1 * 8, s + ga1);
  };
  auto stB = [&](int t, int kh, int bu) {
    const unsigned short* s = Bb + (size_t)t * 64 + kh * 32;
    async_copy16(UB(bu, kh) + c0 * 8, s + ga0);
    async_copy16(UB(bu, kh) + c1 * 8, s + ga1);
  };

  int rdoff = l15 * 32 + ((quad << 3) ^ (((l15 >> 1) & 3) << 3));

  f32x4 zero4 = {0.f, 0.f, 0.f, 0.f};
  f32x4 acc[8][4];
#pragma unroll
  for (int mi = 0; mi < 8; mi++)
#pragma unroll
    for (int ni = 0; ni < 4; ni++) acc[mi][ni] = zero4;

  stA(0, 0, 0); stB(0, 0, 0); stA(0, 1, 0); stB(0, 1, 0); stA(1, 0, 1); stB(1, 0, 1);
  WAITVM(8); BARRIER();

#pragma unroll 2
  for (int t = 0; t < 32; ++t) {
    int bu = t & 1, bn = bu ^ 1;
    int t1 = (t + 1 < 32) ? t + 1 : 31;
    int t2 = (t + 2 < 32) ? t + 2 : 31;
    bf16x8 af[8];
    const unsigned short* pA0 = UA(bu, 0) + wm * 4096 + rdoff;
    const unsigned short* pB0 = UB(bu, 0) + wn * 2048 + rdoff;
    const unsigned short* pA1 = UA(bu, 1) + wm * 4096 + rdoff;
    const unsigned short* pB1 = UB(bu, 1) + wn * 2048 + rdoff;

    // p0
#pragma unroll
    for (int mi = 0; mi < 8; mi++) af[mi] = *(const bf16x8*)(pA0 + mi * 512);
    bf16x8 b0 = *(const bf16x8*)pB0;
    bf16x8 b1 = *(const bf16x8*)(pB0 + 512);
    stA(t1, 1, bn);
    BARRIER(); LGKM0();
    __builtin_amdgcn_s_setprio(1);
#pragma unroll
    for (int mi = 0; mi < 8; mi++) { MFMA16(acc[mi][0], af[mi], b0); MFMA16(acc[mi][1], af[mi], b1); }
    __builtin_amdgcn_s_setprio(0);
    BARRIER();

    // p1
    bf16x8 b2 = *(const bf16x8*)(pB0 + 1024);
    bf16x8 b3 = *(const bf16x8*)(pB0 + 1536);
    stB(t1, 1, bn);
    BARRIER(); LGKM0();
    __builtin_amdgcn_s_setprio(1);
#pragma unroll
    for (int mi = 0; mi < 8; mi++) { MFMA16(acc[mi][2], af[mi], b2); MFMA16(acc[mi][3], af[mi], b3); }
    __builtin_amdgcn_s_setprio(0);
    WAITVM(8);
    BARRIER();

    // p2
#pragma unroll
    for (int mi = 0; mi < 8; mi++) af[mi] = *(const bf16x8*)(pA1 + mi * 512);
    b0 = *(const bf16x8*)pB1;
    b1 = *(const bf16x8*)(pB1 + 512);
    stA(t2, 0, bu);
    BARRIER(); LGKM0();
    __builtin_amdgcn_s_setprio(1);
#pragma unroll
    for (int mi = 0; mi < 8; mi++) { MFMA16(acc[mi][0], af[mi], b0); MFMA16(acc[mi][1], af[mi], b1); }
    __builtin_amdgcn_s_setprio(0);
    BARRIER();

    // p3
    b2 = *(const bf16x8*)(pB1 + 1024);
    b3 = *(const bf16x8*)(pB1 + 1536);
    stB(t2, 0, bu);
    BARRIER(); LGKM0();
    __builtin_amdgcn_s_setprio(1);
#pragma unroll
    for (int mi = 0; mi < 8; mi++) { MFMA16(acc[mi][2], af[mi], b2); MFMA16(acc[mi][3], af[mi], b3); }
    __builtin_amdgcn_s_setprio(0);
    WAITVM(8);
    BARRIER();
  }
  WAITVM(0);

  // ---- epilogue: RoPE for Q/K slots, transposed scatter for V ----
  int hs = (int)(tn0 >> 6) + wn;
  if (hs < 40) {
    float sc = (hs < 32) ? QSC : 1.0f;
    unsigned short* dst0 = (hs < 32) ? qws : kws;
    int hh = (hs < 32) ? hs : (hs - 32);
    float invf0 = __expf(-(float)l15 * (9.210340371976184f / 32.0f));
    float invf1 = invf0 * 0.01f;
#pragma unroll
    for (int mi = 0; mi < 8; mi++)
#pragma unroll
      for (int r = 0; r < 4; r++) {
        size_t gr = tm0 + wm * 128 + mi * 16 + quad * 4 + r;
        int bb = (int)(gr >> 11), s = (int)(gr & 2047);
        float tpos = (float)pos_ids[gr];
        unsigned short* row = dst0 + ((size_t)(bb * ((hs < 32) ? DNH : DKVH) + hh) * DS + s) * DHD;
#pragma unroll
        for (int ni = 0; ni < 2; ni++) {
          float x1 = acc[mi][ni][r], x2 = acc[mi][ni + 2][r];
          float ang = tpos * (ni ? invf1 : invf0);
          float sn, cs;
          __sincosf(ang, &sn, &cs);
          int d = ni * 16 + l15;
          row[d]      = f2b((x1 * cs - x2 * sn) * sc);
          row[d + 32] = f2b((x2 * cs + x1 * sn) * sc);
        }
      }
  } else {
    int vh = hs - 40;
    int bb = (int)(tm0 >> 11);
    int s0 = (int)(tm0 & 2047) + wm * 128 + quad * 4;
#pragma unroll
    for (int mi = 0; mi < 8; mi++)
#pragma unroll
      for (int ni = 0; ni < 4; ni++) {
        int d = ni * 16 + l15;
        us4 o4;
#pragma unroll
        for (int r = 0; r < 4; r++) o4[r] = f2b(acc[mi][ni][r]);
        *(us4*)&vt[((size_t)(bb * DKVH + vh) * DHD + d) * DS + s0 + mi * 16] = o4;
      }
  }
}

// ============================================================================
// 8-phase 128x256 out GEMM (unchanged, round-5)
// ============================================================================
__global__ __launch_bounds__(512, 2)
void gemm_out(const unsigned short* __restrict__ A, const unsigned short* __restrict__ Bt,
              unsigned short* __restrict__ Cb, float* __restrict__ Cf,
              const unsigned short* __restrict__ wqdet) {
  __shared__ __align__(16) unsigned short sm[49152];  // 96 KiB
  int tid = threadIdx.x, lane = tid & 63, wave = tid >> 6;
  int wm = wave >> 2, wn = wave & 3;
  int quad = lane >> 4, l15 = lane & 15;

  int bid = blockIdx.x;
  int wg = (bid & 7) * 32 + (bid >> 3);
  int ty = wg >> 3, tx = wg & 7;
  size_t tm0 = (size_t)ty * 128, tn0 = (size_t)tx * 256;

  const unsigned short* Ab = A + tm0 * 2048;
  const unsigned short* Bb = Bt + tn0 * 2048;

  auto UA = [&](int bu, int kh) { return sm + (bu * 2 + kh) * 4096; };
  auto UB = [&](int bu, int kh) { return sm + 16384 + (bu * 2 + kh) * 8192; };

  int c0 = tid, c1 = tid + 512;
  int r0s = c0 >> 2, r1s = c1 >> 2;
  int cc0 = (c0 & 3) ^ ((r0s >> 1) & 3);
  int cc1 = (c1 & 3) ^ ((r1s >> 1) & 3);
  size_t ga0 = (size_t)r0s * 2048 + cc0 * 8;
  size_t ga1 = (size_t)r1s * 2048 + cc1 * 8;

  auto stA = [&](int t, int kh, int bu) {
    const unsigned short* s = Ab + (size_t)t * 64 + kh * 32;
    async_copy16(UA(bu, kh) + c0 * 8, s + ga0);
  };
  auto stB = [&](int t, int kh, int bu) {
    const unsigned short* s = Bb + (size_t)t * 64 + kh * 32;
    async_copy16(UB(bu, kh) + c0 * 8, s + ga0);
    async_copy16(UB(bu, kh) + c1 * 8, s + ga1);
  };

  int rdoff = l15 * 32 + ((quad << 3) ^ (((l15 >> 1) & 3) << 3));

  f32x4 zero4 = {0.f, 0.f, 0.f, 0.f};
  f32x4 acc[4][4];
#pragma unroll
  for (int mi = 0; mi < 4; mi++)
#pragma unroll
    for (int ni = 0; ni < 4; ni++) acc[mi][ni] = zero4;

  stA(0, 0, 0); stB(0, 0, 0); stA(0, 1, 0); stB(0, 1, 0); stA(1, 0, 1); stB(1, 0, 1);
  WAITVM(6); BARRIER();

#pragma unroll 2
  for (int t = 0; t < 32; ++t) {
    int bu = t & 1, bn = bu ^ 1;
    int t1 = (t + 1 < 32) ? t + 1 : 31;
    int t2 = (t + 2 < 32) ? t + 2 : 31;
    bf16x8 af[4];
    const unsigned short* pA0 = UA(bu, 0) + wm * 2048 + rdoff;
    const unsigned short* pB0 = UB(bu, 0) + wn * 2048 + rdoff;
    const unsigned short* pA1 = UA(bu, 1) + wm * 2048 + rdoff;
    const unsigned short* pB1 = UB(bu, 1) + wn * 2048 + rdoff;

    // p0
#pragma unroll
    for (int mi = 0; mi < 4; mi++) af[mi] = *(const bf16x8*)(pA0 + mi * 512);
    bf16x8 b0 = *(const bf16x8*)pB0;
    bf16x8 b1 = *(const bf16x8*)(pB0 + 512);
    stA(t1, 1, bn);
    BARRIER(); LGKM0();
    __builtin_amdgcn_s_setprio(1);
#pragma unroll
    for (int mi = 0; mi < 4; mi++) { MFMA16(acc[mi][0], af[mi], b0); MFMA16(acc[mi][1], af[mi], b1); }
    __builtin_amdgcn_s_setprio(0);
    BARRIER();

    // p1
    bf16x8 b2 = *(const bf16x8*)(pB0 + 1024);
    bf16x8 b3 = *(const bf16x8*)(pB0 + 1536);
    stB(t1, 1, bn);
    BARRIER(); LGKM0();
    __builtin_amdgcn_s_setprio(1);
#pragma unroll
    for (int mi = 0; mi < 4; mi++) { MFMA16(acc[mi][2], af[mi], b2); MFMA16(acc[mi][3], af[mi], b3); }
    __builtin_amdgcn_s_setprio(0);
    WAITVM(6);
    BARRIER();

    // p2
#pragma unroll
    for (int mi = 0; mi < 4; mi++) af[mi] = *(const bf16x8*)(pA1 + mi * 512);
    b0 = *(const bf16x8*)pB1;
    b1 = *(const bf16x8*)(pB1 + 512);
    stA(t2, 0, bu);
    BARRIER(); LGKM0();
    __builtin_amdgcn_s_setprio(1);
#pragma unroll
    for (int mi = 0; mi < 4; mi++) { MFMA16(acc[mi][0], af[mi], b0); MFMA16(acc[mi][1], af[mi], b1); }
    __builtin_amdgcn_s_setprio(0);
    BARRIER();

    // p3
    b2 = *(const bf16x8*)(pB1 + 1024);
    b3 = *(const bf16x8*)(pB1 + 1536);
    stB(t2, 0, bu);
    BARRIER(); LGKM0();
    __builtin_amdgcn_s_setprio(1);
#pragma unroll
    for (int mi = 0; mi < 4; mi++) { MFMA16(acc[mi][2], af[mi], b2); MFMA16(acc[mi][3], af[mi], b3); }
    __builtin_amdgcn_s_setprio(0);
    WAITVM(6);
    BARRIER();
  }
  WAITVM(0);

  int mode = detect_inline(wqdet);
#pragma unroll
  for (int mi = 0; mi < 4; mi++)
#pragma unroll
    for (int ni = 0; ni < 4; ni++)
#pragma unroll
      for (int r = 0; r < 4; r++) {
        size_t gr = tm0 + wm * 64 + mi * 16 + quad * 4 + r;
        size_t gc = tn0 + wn * 64 + ni * 16 + l15;
        float v = acc[mi][ni][r];
        if (mode) Cf[gr * 2048 + gc] = v;
        else      Cb[gr * 2048 + gc] = f2b(v);
      }
}

// ============================================================================
// causal GQA flash attention v5: dual q-tile co-processing.
// Block (qt) processes q-tiles A=qt and B=31-qt over ONE kv sweep:
//   shared iters t=0..qt: both frags (K-frag ds_reads + staging + barriers
//   amortized over 2x MFMA); solo iters t=qt+1..31-qt: frag B only.
// K/V staged once per tile (-26% staging traffic); one prologue drain.
// Softmax path byte-identical to round-5 (online max + defer-max THR=8).
// s_setprio(1) around MFMA clusters (T5, attn regime).
//  LDS: 40960 B -> 4 blocks/CU
// ============================================================================
__global__ __launch_bounds__(256, 4)
void flash_attn(const unsigned short* __restrict__ q, const unsigned short* __restrict__ k,
                const unsigned short* __restrict__ vt, unsigned short* __restrict__ ctx) {
  __shared__ __align__(16) unsigned short lK[2][2][64 * 32];  // [buf][half] 16 KiB
  __shared__ __align__(16) unsigned short lV[2][2][64 * 32];  // [buf][half] 16 KiB
  __shared__ __align__(16) unsigned short lP[4][16 * 64];     // 8 KiB (A/B sequential reuse)
  int tid = threadIdx.x, lane = tid & 63, wave = tid >> 6;
  int quad = lane >> 4, l15 = lane & 15;
  int bh = blockIdx.y, b = bh >> 5, h = bh & 31, kvh = h >> 2;
  const unsigned short* qb = q + (size_t)(b * DNH + h) * DS * DHD;
  const unsigned short* kb = k + (size_t)(b * DKVH + kvh) * DS * DHD;
  const unsigned short* vb = vt + (size_t)(b * DKVH + kvh) * DHD * DS;
  unsigned short* lPw = lP[wave];
  int r4 = tid >> 2;
  int cc8 = ((tid & 3) ^ ((r4 >> 1) & 3)) * 8;   // inverse-swizzled source chunk (K,V)
  int swz = ((l15 >> 1) & 3) << 3;               // K/V read-side XOR (shorts)
  int pswz = (l15 & 7) << 3;                     // P row-XOR (shorts)
  int ql = wave * 16 + l15;                      // q-row within 64-tile

  int qt = blockIdx.x;                           // 0..15 -> tiles A=qt, B=31-qt
  int ntA = qt + 1, ntB = 32 - qt;               // ntA < ntB always
  int q0A = qt * 64, q0B = (31 - qt) * 64;

  const unsigned short* qpA = qb + (size_t)(q0A + ql) * DHD + quad * 8;
  const unsigned short* qpB = qb + (size_t)(q0B + ql) * DHD + quad * 8;
  bf16x8 qfA0 = *(const bf16x8*)qpA;
  bf16x8 qfA1 = *(const bf16x8*)(qpA + 32);
  bf16x8 qfB0 = *(const bf16x8*)qpB;
  bf16x8 qfB1 = *(const bf16x8*)(qpB + 32);

  f32x4 zero4 = {0.f, 0.f, 0.f, 0.f};
  f32x4 oA[4], oB[4];
#pragma unroll
  for (int dj = 0; dj < 4; dj++) { oA[dj] = zero4; oB[dj] = zero4; }
  float mA = -1e30f, lA = 0.f, mB = -1e30f, lB = 0.f;

  auto stage = [&](int t, int buf) {
    const unsigned short* sk = kb + (size_t)(t * 64 + r4) * DHD + cc8;
    async_copy16(&lK[buf][0][tid * 8], sk);
    async_copy16(&lK[buf][1][tid * 8], sk + 32);
    const unsigned short* sv = vb + (size_t)r4 * DS + t * 64 + cc8;
    async_copy16(&lV[buf][0][tid * 8], sv);
    async_copy16(&lV[buf][1][tid * 8], sv + 32);
  };

  // softmax + PV for one fragment (round-5 math, parameterized)
  auto smax_pv = [&](f32x4 (&sacc)[4], float& mrow, float& lrow, f32x4 (&oacc)[4],
                     int cur, int maskdiag) {
    if (maskdiag) {
#pragma unroll
      for (int nj = 0; nj < 4; nj++)
#pragma unroll
        for (int r = 0; r < 4; r++)
          if (nj * 16 + quad * 4 + r > ql) sacc[nj][r] = -1e30f;
    }
    float a0 = fmaxf(fmaxf(sacc[0][0], sacc[0][1]), sacc[0][2]);
    float a1 = fmaxf(fmaxf(sacc[0][3], sacc[1][0]), sacc[1][1]);
    float a2 = fmaxf(fmaxf(sacc[1][2], sacc[1][3]), sacc[2][0]);
    float a3 = fmaxf(fmaxf(sacc[2][1], sacc[2][2]), sacc[2][3]);
    float a4 = fmaxf(fmaxf(sacc[3][0], sacc[3][1]), sacc[3][2]);
    float tm = fmaxf(fmaxf(fmaxf(a0, a1), fmaxf(a2, a3)), fmaxf(a4, sacc[3][3]));
    tm = fmaxf(tm, __shfl_xor(tm, 16));
    tm = fmaxf(tm, __shfl_xor(tm, 32));
    // defer-max: rescale only when running max grew by > 8 (log2 units)
    if (!__all(tm <= mrow + 8.f)) {
      float mn = fmaxf(mrow, tm);
      float alpha = __builtin_amdgcn_exp2f(mrow - mn);
      mrow = mn;
      lrow *= alpha;
#pragma unroll
      for (int dj = 0; dj < 4; dj++)
#pragma unroll
        for (int r = 0; r < 4; r++) oacc[dj][r] *= alpha;
    }
    float rs = 0.f;
#pragma unroll
    for (int nj = 0; nj < 4; nj++)
#pragma unroll
      for (int r = 0; r < 4; r++) {
        float e = __builtin_amdgcn_exp2f(sacc[nj][r] - mrow);
        sacc[nj][r] = e;
        rs += e;
      }
    rs += __shfl_xor(rs, 16);
    rs += __shfl_xor(rs, 32);
    lrow += rs;
#pragma unroll
    for (int nj = 0; nj < 4; nj++) {
      u32x2 w2;
      w2[0] = cvt_pk_bf16(sacc[nj][0], sacc[nj][1]);
      w2[1] = cvt_pk_bf16(sacc[nj][2], sacc[nj][3]);
      *(u32x2*)&lPw[l15 * 64 + ((nj * 16 + quad * 4) ^ pswz)] = w2;
    }
    bf16x8 pf0 = *(const bf16x8*)&lPw[l15 * 64 + ((quad * 8) ^ pswz)];
    bf16x8 pf1 = *(const bf16x8*)&lPw[l15 * 64 + ((32 + quad * 8) ^ pswz)];
    __builtin_amdgcn_s_setprio(1);
#pragma unroll
    for (int dj = 0; dj < 4; dj++) {
      int ro = (dj * 16 + l15) * 32 + ((quad * 8) ^ swz);
      bf16x8 vf0 = *(const bf16x8*)&lV[cur][0][ro];
      bf16x8 vf1 = *(const bf16x8*)&lV[cur][1][ro];
      MFMA16(oacc[dj], vf0, pf0);
      MFMA16(oacc[dj], vf1, pf1);
    }
    __builtin_amdgcn_s_setprio(0);
  };

  // prologue: stage tile 0 -> buf 0
  stage(0, 0);
  WAITVM(0); BARRIER();

  int cur = 0;
  // ---- shared iterations: frags A and B, K fragments reused ----
  for (int t = 0; t < ntA; t++) {
    stage(t + 1, cur ^ 1);           // t+1 <= ntA <= ntB-1: always a valid tile
    f32x4 sA[4], sB[4];
    __builtin_amdgcn_s_setprio(1);
#pragma unroll
    for (int nj = 0; nj < 4; nj++) {
      int ro = (nj * 16 + l15) * 32 + ((quad * 8) ^ swz);
      bf16x8 kf0 = *(const bf16x8*)&lK[cur][0][ro];
      bf16x8 kf1 = *(const bf16x8*)&lK[cur][1][ro];
      sA[nj] = zero4;
      MFMA16(sA[nj], kf0, qfA0);
      MFMA16(sA[nj], kf1, qfA1);
      sB[nj] = zero4;
      MFMA16(sB[nj], kf0, qfB0);
      MFMA16(sB[nj], kf1, qfB1);
    }
    __builtin_amdgcn_s_setprio(0);
    smax_pv(sA, mA, lA, oA, cur, t == ntA - 1);   // A hits diagonal at last shared iter
    smax_pv(sB, mB, lB, oB, cur, 0);              // B diag is in solo range (t<=qt<31-qt)
    WAITVM(0); BARRIER();
    cur ^= 1;
  }
  // ---- solo iterations: frag B only ----
  for (int t = ntA; t < ntB; t++) {
    if (t + 1 < ntB) stage(t + 1, cur ^ 1);
    f32x4 sB[4];
    __builtin_amdgcn_s_setprio(1);
#pragma unroll
    for (int nj = 0; nj < 4; nj++) {
      int ro = (nj * 16 + l15) * 32 + ((quad * 8) ^ swz);
      bf16x8 kf0 = *(const bf16x8*)&lK[cur][0][ro];
      bf16x8 kf1 = *(const bf16x8*)&lK[cur][1][ro];
      sB[nj] = zero4;
      MFMA16(sB[nj], kf0, qfB0);
      MFMA16(sB[nj], kf1, qfB1);
    }
    __builtin_amdgcn_s_setprio(0);
    smax_pv(sB, mB, lB, oB, cur, t == ntB - 1);
    WAITVM(0); BARRIER();
    cur ^= 1;
  }

  // ---- epilogue ----
  auto wout = [&](f32x4 (&oacc)[4], float lrow, int q0) {
    float inv = __builtin_amdgcn_rcpf(lrow);
    size_t orow = ((size_t)b * DS + q0 + ql) * (DNH * DHD) + (size_t)h * DHD;
#pragma unroll
    for (int dj = 0; dj < 4; dj++) {
      u32x2 o2;
      o2[0] = cvt_pk_bf16(oacc[dj][0] * inv, oacc[dj][1] * inv);
      o2[1] = cvt_pk_bf16(oacc[dj][2] * inv, oacc[dj][3] * inv);
      *(u32x2*)&ctx[orow + dj * 16 + quad * 4] = o2;
    }
  };
  wout(oA, lA, q0A);
  wout(oB, lB, q0B);
}

extern "C" void kernel_launch(void* const* d_in, const int* in_sizes, int n_in,
                              void* d_out, int out_size, void* d_ws, size_t ws_size,
                              hipStream_t stream) {
  (void)in_sizes; (void)n_in; (void)out_size; (void)ws_size;
  const void* hs = d_in[0];
  const int* pos = (const int*)d_in[2];
  const void* wq = d_in[3];
  const void* wk = d_in[4];
  const void* wv = d_in[5];
  const void* wo = d_in[6];

  char* ws = (char*)d_ws;
  size_t off = 0;
  auto take = [&](size_t bytes) -> char* {
    char* p = ws + off;
    off += (bytes + 255) & ~(size_t)255;
    return p;
  };
  unsigned short* xb    = (unsigned short*)take((size_t)DM * DH * 2);
  unsigned short* wtqkv = (unsigned short*)take((size_t)DNQKV * DH * 2);
  unsigned short* wto   = (unsigned short*)take((size_t)DH * DH * 2);
  unsigned short* qws   = (unsigned short*)take((size_t)DB * DNH * DS * DHD * 2);
  unsigned short* kws   = (unsigned short*)take((size_t)DB * DKVH * DS * DHD * 2);
  unsigned short* vtws  = (unsigned short*)take((size_t)DB * DKVH * DS * DHD * 2);
  unsigned short* ctx   = (unsigned short*)take((size_t)DM * DNH * DHD * 2);

  prep<<<14336, 256, 0, stream>>>(hs, wq, wk, wv, wo, xb, wtqkv, wto);

  gemm_qkv<<<dim3(192), 512, 0, stream>>>(xb, wtqkv, pos, qws, kws, vtws);

  flash_attn<<<dim3(16, DB * DNH), 256, 0, stream>>>(qws, kws, vtws, ctx);

  gemm_out<<<dim3(256), 512, 0, stream>>>(ctx, wto, (unsigned short*)d_out, (float*)d_out,
                                          (const unsigned short*)wq);
}

// Round 7
// 300.375 us; speedup vs baseline: 1.0206x; 1.0206x over previous
//
#include <hip/hip_runtime.h>
#include <hip/hip_bf16.h>

// ---- problem constants ----
#define DB   2
#define DS   2048
#define DH   2048
#define DNH  32
#define DKVH 8
#define DHD  64
#define DM   4096    // B*S
#define DNQKV 3072   // NH*HD + 2*KVH*HD

typedef __attribute__((ext_vector_type(8))) short bf16x8;
typedef __attribute__((ext_vector_type(4))) float f32x4;
typedef __attribute__((ext_vector_type(8))) unsigned short us8;
typedef __attribute__((ext_vector_type(4))) unsigned short us4;
typedef __attribute__((ext_vector_type(2))) unsigned int u32x2;

__device__ __forceinline__ float b2f(unsigned short u) {
  unsigned int x = ((unsigned int)u) << 16;
  return __builtin_bit_cast(float, x);
}
__device__ __forceinline__ unsigned short f2b(float f) {
  unsigned int u = __builtin_bit_cast(unsigned int, f);
  return (unsigned short)((u + 0x8000u) >> 16);
}
__device__ __forceinline__ unsigned int cvt_pk_bf16(float lo, float hi) {
  unsigned int r;
  asm("v_cvt_pk_bf16_f32 %0, %1, %2" : "=v"(r) : "v"(lo), "v"(hi));
  return r;
}
__device__ __forceinline__ void async_copy16(void* lds, const void* g) {
  __builtin_amdgcn_global_load_lds((const __attribute__((address_space(1))) void*)g,
                                   (__attribute__((address_space(3))) void*)lds,
                                   16, 0, 0);
}

// raw barrier (no waitcnt drain) + compiler memory fences
#define BARRIER() do { asm volatile("" ::: "memory"); __builtin_amdgcn_s_barrier(); asm volatile("" ::: "memory"); } while (0)
#define LGKM0()   asm volatile("s_waitcnt lgkmcnt(0)" ::: "memory")
#define WAITVM(n) asm volatile("s_waitcnt vmcnt(" #n ")" ::: "memory")
#define MFMA16(d, a, bb) (d) = __builtin_amdgcn_mfma_f32_16x16x32_bf16((a), (bb), (d), 0, 0, 0)

// ---- inline dtype detector: wave-reduce over first 256 shorts of Wq ----
__device__ __forceinline__ int detect_inline(const unsigned short* __restrict__ w) {
  int t = threadIdx.x & 63;
  int trips = 0;
#pragma unroll
  for (int i = 0; i < 4; i++) {
    unsigned short u = w[t * 4 + i];
    int e = (u >> 7) & 0xFF;
    if (e >= 161 || (e <= 93 && e != 0)) trips++;
  }
#pragma unroll
  for (int off = 32; off > 0; off >>= 1) trips += __shfl_down(trips, off);
  return __shfl(trips, 0) >= 8;   // 1 = fp32 I/O, 0 = bf16
}

// ============================================================================
// fused preprocessing: one launch. (unchanged)
// ============================================================================
__global__ __launch_bounds__(256)
void prep(const void* __restrict__ hs, const void* __restrict__ wq,
          const void* __restrict__ wk, const void* __restrict__ wv,
          const void* __restrict__ wo,
          unsigned short* __restrict__ xb, unsigned short* __restrict__ wtqkv,
          unsigned short* __restrict__ wto) {
  __shared__ float tile[32][33];
  int mode = detect_inline((const unsigned short*)wq);
  int bid = blockIdx.x;
  if (bid < 4096) {
    int i = (bid * 256 + threadIdx.x) * 8;
    if (mode) {
      const float* f = (const float*)hs;
      us8 o;
#pragma unroll
      for (int j = 0; j < 8; j++) o[j] = f2b(f[i + j]);
      *(us8*)&xb[i] = o;
    } else {
      *(us8*)&xb[i] = *(const us8*)((const unsigned short*)hs + i);
    }
    return;
  }
  const void* win; unsigned short* out; int C, bx, by;
  if (bid < 8192)       { int l = bid - 4096;  win = wq; out = wtqkv;                         C = 2048; bx = l & 63; by = l >> 6; }
  else if (bid < 9216)  { int l = bid - 8192;  win = wk; out = wtqkv + (size_t)2048 * 2048;   C = 512;  bx = l & 15; by = l >> 4; }
  else if (bid < 10240) { int l = bid - 9216;  win = wv; out = wtqkv + (size_t)2560 * 2048;   C = 512;  bx = l & 15; by = l >> 4; }
  else                  { int l = bid - 10240; win = wo; out = wto;                           C = 2048; bx = l & 63; by = l >> 6; }
  int c0 = bx * 32, r0 = by * 32;
  int tx = threadIdx.x & 31, ty = threadIdx.x >> 5;
  if (mode) {
    const float* f = (const float*)win;
    for (int i = ty; i < 32; i += 8) tile[i][tx] = f[(size_t)(r0 + i) * C + c0 + tx];
  } else {
    const unsigned short* bsrc = (const unsigned short*)win;
    for (int i = ty; i < 32; i += 8) tile[i][tx] = b2f(bsrc[(size_t)(r0 + i) * C + c0 + tx]);
  }
  __syncthreads();
  for (int i = ty; i < 32; i += 8) out[(size_t)(c0 + i) * 2048 + r0 + tx] = f2b(tile[tx][i]);
}

#define QSC 0.18033688011112042f   // (1/8) * log2(e)

// ============================================================================
// 8-phase 256x256 QKV GEMM + RoPE + head-major scatter. (unchanged)
// ============================================================================
__global__ __launch_bounds__(512, 2)
void gemm_qkv(const unsigned short* __restrict__ A, const unsigned short* __restrict__ Bt,
              const int* __restrict__ pos_ids,
              unsigned short* __restrict__ qws, unsigned short* __restrict__ kws,
              unsigned short* __restrict__ vt) {
  __shared__ __align__(16) unsigned short sm[65536];  // 128 KiB
  int tid = threadIdx.x, lane = tid & 63, wave = tid >> 6;
  int wm = wave >> 2, wn = wave & 3;           // 2 x 4 waves, wave tile 128x64
  int quad = lane >> 4, l15 = lane & 15;

  int bid = blockIdx.x;                         // 192 blocks, 192 % 8 == 0
  int wg = (bid & 7) * 24 + (bid >> 3);         // XCD-contiguous chunks of 24
  int ty = wg / 12, tx = wg - ty * 12;
  size_t tm0 = (size_t)ty * 256, tn0 = (size_t)tx * 256;

  const unsigned short* Ab = A + tm0 * 2048;
  const unsigned short* Bb = Bt + tn0 * 2048;

  auto UA = [&](int bu, int kh) { return sm + (bu * 2 + kh) * 8192; };
  auto UB = [&](int bu, int kh) { return sm + 32768 + (bu * 2 + kh) * 8192; };

  int c0 = tid, c1 = tid + 512;
  int r0s = c0 >> 2, r1s = c1 >> 2;
  int cc0 = (c0 & 3) ^ ((r0s >> 1) & 3);
  int cc1 = (c1 & 3) ^ ((r1s >> 1) & 3);
  size_t ga0 = (size_t)r0s * 2048 + cc0 * 8;
  size_t ga1 = (size_t)r1s * 2048 + cc1 * 8;

  auto stA = [&](int t, int kh, int bu) {
    const unsigned short* s = Ab + (size_t)t * 64 + kh * 32;
    async_copy16(UA(bu, kh) + c0 * 8, s + ga0);
    async_copy16(UA(bu, kh) + c1 * 8, s + ga1);
  };
  auto stB = [&](int t, int kh, int bu) {
    const unsigned short* s = Bb + (size_t)t * 64 + kh * 32;
    async_copy16(UB(bu, kh) + c0 * 8, s + ga0);
    async_copy16(UB(bu, kh) + c1 * 8, s + ga1);
  };

  int rdoff = l15 * 32 + ((quad << 3) ^ (((l15 >> 1) & 3) << 3));

  f32x4 zero4 = {0.f, 0.f, 0.f, 0.f};
  f32x4 acc[8][4];
#pragma unroll
  for (int mi = 0; mi < 8; mi++)
#pragma unroll
    for (int ni = 0; ni < 4; ni++) acc[mi][ni] = zero4;

  stA(0, 0, 0); stB(0, 0, 0); stA(0, 1, 0); stB(0, 1, 0); stA(1, 0, 1); stB(1, 0, 1);
  WAITVM(8); BARRIER();

#pragma unroll 2
  for (int t = 0; t < 32; ++t) {
    int bu = t & 1, bn = bu ^ 1;
    int t1 = (t + 1 < 32) ? t + 1 : 31;
    int t2 = (t + 2 < 32) ? t + 2 : 31;
    bf16x8 af[8];
    const unsigned short* pA0 = UA(bu, 0) + wm * 4096 + rdoff;
    const unsigned short* pB0 = UB(bu, 0) + wn * 2048 + rdoff;
    const unsigned short* pA1 = UA(bu, 1) + wm * 4096 + rdoff;
    const unsigned short* pB1 = UB(bu, 1) + wn * 2048 + rdoff;

    // p0
#pragma unroll
    for (int mi = 0; mi < 8; mi++) af[mi] = *(const bf16x8*)(pA0 + mi * 512);
    bf16x8 b0 = *(const bf16x8*)pB0;
    bf16x8 b1 = *(const bf16x8*)(pB0 + 512);
    stA(t1, 1, bn);
    BARRIER(); LGKM0();
    __builtin_amdgcn_s_setprio(1);
#pragma unroll
    for (int mi = 0; mi < 8; mi++) { MFMA16(acc[mi][0], af[mi], b0); MFMA16(acc[mi][1], af[mi], b1); }
    __builtin_amdgcn_s_setprio(0);
    BARRIER();

    // p1
    bf16x8 b2 = *(const bf16x8*)(pB0 + 1024);
    bf16x8 b3 = *(const bf16x8*)(pB0 + 1536);
    stB(t1, 1, bn);
    BARRIER(); LGKM0();
    __builtin_amdgcn_s_setprio(1);
#pragma unroll
    for (int mi = 0; mi < 8; mi++) { MFMA16(acc[mi][2], af[mi], b2); MFMA16(acc[mi][3], af[mi], b3); }
    __builtin_amdgcn_s_setprio(0);
    WAITVM(8);
    BARRIER();

    // p2
#pragma unroll
    for (int mi = 0; mi < 8; mi++) af[mi] = *(const bf16x8*)(pA1 + mi * 512);
    b0 = *(const bf16x8*)pB1;
    b1 = *(const bf16x8*)(pB1 + 512);
    stA(t2, 0, bu);
    BARRIER(); LGKM0();
    __builtin_amdgcn_s_setprio(1);
#pragma unroll
    for (int mi = 0; mi < 8; mi++) { MFMA16(acc[mi][0], af[mi], b0); MFMA16(acc[mi][1], af[mi], b1); }
    __builtin_amdgcn_s_setprio(0);
    BARRIER();

    // p3
    b2 = *(const bf16x8*)(pB1 + 1024);
    b3 = *(const bf16x8*)(pB1 + 1536);
    stB(t2, 0, bu);
    BARRIER(); LGKM0();
    __builtin_amdgcn_s_setprio(1);
#pragma unroll
    for (int mi = 0; mi < 8; mi++) { MFMA16(acc[mi][2], af[mi], b2); MFMA16(acc[mi][3], af[mi], b3); }
    __builtin_amdgcn_s_setprio(0);
    WAITVM(8);
    BARRIER();
  }
  WAITVM(0);

  // ---- epilogue: RoPE for Q/K slots, transposed scatter for V ----
  int hs = (int)(tn0 >> 6) + wn;
  if (hs < 40) {
    float sc = (hs < 32) ? QSC : 1.0f;
    unsigned short* dst0 = (hs < 32) ? qws : kws;
    int hh = (hs < 32) ? hs : (hs - 32);
    float invf0 = __expf(-(float)l15 * (9.210340371976184f / 32.0f));
    float invf1 = invf0 * 0.01f;
#pragma unroll
    for (int mi = 0; mi < 8; mi++)
#pragma unroll
      for (int r = 0; r < 4; r++) {
        size_t gr = tm0 + wm * 128 + mi * 16 + quad * 4 + r;
        int bb = (int)(gr >> 11), s = (int)(gr & 2047);
        float tpos = (float)pos_ids[gr];
        unsigned short* row = dst0 + ((size_t)(bb * ((hs < 32) ? DNH : DKVH) + hh) * DS + s) * DHD;
#pragma unroll
        for (int ni = 0; ni < 2; ni++) {
          float x1 = acc[mi][ni][r], x2 = acc[mi][ni + 2][r];
          float ang = tpos * (ni ? invf1 : invf0);
          float sn, cs;
          __sincosf(ang, &sn, &cs);
          int d = ni * 16 + l15;
          row[d]      = f2b((x1 * cs - x2 * sn) * sc);
          row[d + 32] = f2b((x2 * cs + x1 * sn) * sc);
        }
      }
  } else {
    int vh = hs - 40;
    int bb = (int)(tm0 >> 11);
    int s0 = (int)(tm0 & 2047) + wm * 128 + quad * 4;
#pragma unroll
    for (int mi = 0; mi < 8; mi++)
#pragma unroll
      for (int ni = 0; ni < 4; ni++) {
        int d = ni * 16 + l15;
        us4 o4;
#pragma unroll
        for (int r = 0; r < 4; r++) o4[r] = f2b(acc[mi][ni][r]);
        *(us4*)&vt[((size_t)(bb * DKVH + vh) * DHD + d) * DS + s0 + mi * 16] = o4;
      }
  }
}

// ============================================================================
// 8-phase 128x256 out GEMM (unchanged)
// ============================================================================
__global__ __launch_bounds__(512, 2)
void gemm_out(const unsigned short* __restrict__ A, const unsigned short* __restrict__ Bt,
              unsigned short* __restrict__ Cb, float* __restrict__ Cf,
              const unsigned short* __restrict__ wqdet) {
  __shared__ __align__(16) unsigned short sm[49152];  // 96 KiB
  int tid = threadIdx.x, lane = tid & 63, wave = tid >> 6;
  int wm = wave >> 2, wn = wave & 3;
  int quad = lane >> 4, l15 = lane & 15;

  int bid = blockIdx.x;
  int wg = (bid & 7) * 32 + (bid >> 3);
  int ty = wg >> 3, tx = wg & 7;
  size_t tm0 = (size_t)ty * 128, tn0 = (size_t)tx * 256;

  const unsigned short* Ab = A + tm0 * 2048;
  const unsigned short* Bb = Bt + tn0 * 2048;

  auto UA = [&](int bu, int kh) { return sm + (bu * 2 + kh) * 4096; };
  auto UB = [&](int bu, int kh) { return sm + 16384 + (bu * 2 + kh) * 8192; };

  int c0 = tid, c1 = tid + 512;
  int r0s = c0 >> 2, r1s = c1 >> 2;
  int cc0 = (c0 & 3) ^ ((r0s >> 1) & 3);
  int cc1 = (c1 & 3) ^ ((r1s >> 1) & 3);
  size_t ga0 = (size_t)r0s * 2048 + cc0 * 8;
  size_t ga1 = (size_t)r1s * 2048 + cc1 * 8;

  auto stA = [&](int t, int kh, int bu) {
    const unsigned short* s = Ab + (size_t)t * 64 + kh * 32;
    async_copy16(UA(bu, kh) + c0 * 8, s + ga0);
  };
  auto stB = [&](int t, int kh, int bu) {
    const unsigned short* s = Bb + (size_t)t * 64 + kh * 32;
    async_copy16(UB(bu, kh) + c0 * 8, s + ga0);
    async_copy16(UB(bu, kh) + c1 * 8, s + ga1);
  };

  int rdoff = l15 * 32 + ((quad << 3) ^ (((l15 >> 1) & 3) << 3));

  f32x4 zero4 = {0.f, 0.f, 0.f, 0.f};
  f32x4 acc[4][4];
#pragma unroll
  for (int mi = 0; mi < 4; mi++)
#pragma unroll
    for (int ni = 0; ni < 4; ni++) acc[mi][ni] = zero4;

  stA(0, 0, 0); stB(0, 0, 0); stA(0, 1, 0); stB(0, 1, 0); stA(1, 0, 1); stB(1, 0, 1);
  WAITVM(6); BARRIER();

#pragma unroll 2
  for (int t = 0; t < 32; ++t) {
    int bu = t & 1, bn = bu ^ 1;
    int t1 = (t + 1 < 32) ? t + 1 : 31;
    int t2 = (t + 2 < 32) ? t + 2 : 31;
    bf16x8 af[4];
    const unsigned short* pA0 = UA(bu, 0) + wm * 2048 + rdoff;
    const unsigned short* pB0 = UB(bu, 0) + wn * 2048 + rdoff;
    const unsigned short* pA1 = UA(bu, 1) + wm * 2048 + rdoff;
    const unsigned short* pB1 = UB(bu, 1) + wn * 2048 + rdoff;

    // p0
#pragma unroll
    for (int mi = 0; mi < 4; mi++) af[mi] = *(const bf16x8*)(pA0 + mi * 512);
    bf16x8 b0 = *(const bf16x8*)pB0;
    bf16x8 b1 = *(const bf16x8*)(pB0 + 512);
    stA(t1, 1, bn);
    BARRIER(); LGKM0();
    __builtin_amdgcn_s_setprio(1);
#pragma unroll
    for (int mi = 0; mi < 4; mi++) { MFMA16(acc[mi][0], af[mi], b0); MFMA16(acc[mi][1], af[mi], b1); }
    __builtin_amdgcn_s_setprio(0);
    BARRIER();

    // p1
    bf16x8 b2 = *(const bf16x8*)(pB0 + 1024);
    bf16x8 b3 = *(const bf16x8*)(pB0 + 1536);
    stB(t1, 1, bn);
    BARRIER(); LGKM0();
    __builtin_amdgcn_s_setprio(1);
#pragma unroll
    for (int mi = 0; mi < 4; mi++) { MFMA16(acc[mi][2], af[mi], b2); MFMA16(acc[mi][3], af[mi], b3); }
    __builtin_amdgcn_s_setprio(0);
    WAITVM(6);
    BARRIER();

    // p2
#pragma unroll
    for (int mi = 0; mi < 4; mi++) af[mi] = *(const bf16x8*)(pA1 + mi * 512);
    b0 = *(const bf16x8*)pB1;
    b1 = *(const bf16x8*)(pB1 + 512);
    stA(t2, 0, bu);
    BARRIER(); LGKM0();
    __builtin_amdgcn_s_setprio(1);
#pragma unroll
    for (int mi = 0; mi < 4; mi++) { MFMA16(acc[mi][0], af[mi], b0); MFMA16(acc[mi][1], af[mi], b1); }
    __builtin_amdgcn_s_setprio(0);
    BARRIER();

    // p3
    b2 = *(const bf16x8*)(pB1 + 1024);
    b3 = *(const bf16x8*)(pB1 + 1536);
    stB(t2, 0, bu);
    BARRIER(); LGKM0();
    __builtin_amdgcn_s_setprio(1);
#pragma unroll
    for (int mi = 0; mi < 4; mi++) { MFMA16(acc[mi][2], af[mi], b2); MFMA16(acc[mi][3], af[mi], b3); }
    __builtin_amdgcn_s_setprio(0);
    WAITVM(6);
    BARRIER();
  }
  WAITVM(0);

  int mode = detect_inline(wqdet);
#pragma unroll
  for (int mi = 0; mi < 4; mi++)
#pragma unroll
    for (int ni = 0; ni < 4; ni++)
#pragma unroll
      for (int r = 0; r < 4; r++) {
        size_t gr = tm0 + wm * 64 + mi * 16 + quad * 4 + r;
        size_t gc = tn0 + wn * 64 + ni * 16 + l15;
        float v = acc[mi][ni][r];
        if (mode) Cf[gr * 2048 + gc] = v;
        else      Cb[gr * 2048 + gc] = f2b(v);
      }
}

// ============================================================================
// causal GQA flash attention v7: QBLK=128, 8 waves, dual q-tile co-processing.
// Block (bh, qt) handles q-rows [qt*128,qt*128+128) (A) and
// [(15-qt)*128, +128) (B) over one kv sweep. 512 threads stage one 64x64
// K tile + one V tile with 1 load each (was 2+2 at QBLK=64). Same math as
// round-5/6 (online max + defer-max THR=8, poison-safe). qt in blockIdx.y so
// CU-stride block assignment mixes durations (W = 33.2-0.8qt).
// Wave-dependent diagonal: waves 0-3 hit diag one tile early and run one
// fully-masked tile on the last shared iter (exp2(-inf)=0, exact).
//  LDS: 16K K-dbuf + 16K V-dbuf + 16K P = 48K -> 512 blocks = 2/CU resident
// ============================================================================
__global__ __launch_bounds__(512, 4)
void flash_attn(const unsigned short* __restrict__ q, const unsigned short* __restrict__ k,
                const unsigned short* __restrict__ vt, unsigned short* __restrict__ ctx) {
  __shared__ __align__(16) unsigned short lK[2][2][64 * 32];  // 16 KiB
  __shared__ __align__(16) unsigned short lV[2][2][64 * 32];  // 16 KiB
  __shared__ __align__(16) unsigned short lP[8][16 * 64];     // 16 KiB
  int tid = threadIdx.x, lane = tid & 63, wave = tid >> 6;    // 8 waves
  int quad = lane >> 4, l15 = lane & 15;
  int bh = blockIdx.x, b = bh >> 5, h = bh & 31, kvh = h >> 2;
  const unsigned short* qb = q + (size_t)(b * DNH + h) * DS * DHD;
  const unsigned short* kb = k + (size_t)(b * DKVH + kvh) * DS * DHD;
  const unsigned short* vb = vt + (size_t)(b * DKVH + kvh) * DHD * DS;
  unsigned short* lPw = lP[wave];
  // staging: 512 threads cover one full 64x64 bf16 tile per call (1 load each)
  int shalf = tid >> 8, r8 = tid & 255;
  int rowS = r8 >> 2;
  int cc8 = ((r8 & 3) ^ ((rowS >> 1) & 3)) * 8;  // inverse-swizzled source chunk
  int swz = ((l15 >> 1) & 3) << 3;               // K/V read-side XOR (shorts)
  int pswz = (l15 & 7) << 3;                     // P row-XOR (shorts)
  int ql = wave * 16 + l15;                      // q-row within 128-tile

  int qt = blockIdx.y;                           // 0..7
  int ntA = 2 * qt + 2, ntB = 32 - 2 * qt;       // ntA < ntB always
  int qAg = qt * 128 + ql, qBg = (15 - qt) * 128 + ql;

  const unsigned short* qpA = qb + (size_t)qAg * DHD + quad * 8;
  const unsigned short* qpB = qb + (size_t)qBg * DHD + quad * 8;
  bf16x8 qfA0 = *(const bf16x8*)qpA, qfA1 = *(const bf16x8*)(qpA + 32);
  bf16x8 qfB0 = *(const bf16x8*)qpB, qfB1 = *(const bf16x8*)(qpB + 32);

  f32x4 zero4 = {0.f, 0.f, 0.f, 0.f};
  f32x4 oA[4], oB[4];
#pragma unroll
  for (int dj = 0; dj < 4; dj++) { oA[dj] = zero4; oB[dj] = zero4; }
  float mA = -1e30f, lA = 0.f, mB = -1e30f, lB = 0.f;

  auto stage = [&](int t, int buf) {
    const unsigned short* sk = kb + (size_t)(t * 64 + rowS) * DHD + shalf * 32 + cc8;
    async_copy16(&lK[buf][shalf][r8 * 8], sk);
    const unsigned short* sv = vb + (size_t)rowS * DS + t * 64 + shalf * 32 + cc8;
    async_copy16(&lV[buf][shalf][r8 * 8], sv);
  };

  // softmax + PV for one fragment (round-5 math; mask vs global kv index)
  auto smax_pv = [&](f32x4 (&sacc)[4], float& mrow, float& lrow, f32x4 (&oacc)[4],
                     int cur, int kv0, int qg, bool domask) {
    if (domask) {
#pragma unroll
      for (int nj = 0; nj < 4; nj++)
#pragma unroll
        for (int r = 0; r < 4; r++)
          if (kv0 + nj * 16 + quad * 4 + r > qg) sacc[nj][r] = -1e30f;
    }
    float a0 = fmaxf(fmaxf(sacc[0][0], sacc[0][1]), sacc[0][2]);
    float a1 = fmaxf(fmaxf(sacc[0][3], sacc[1][0]), sacc[1][1]);
    float a2 = fmaxf(fmaxf(sacc[1][2], sacc[1][3]), sacc[2][0]);
    float a3 = fmaxf(fmaxf(sacc[2][1], sacc[2][2]), sacc[2][3]);
    float a4 = fmaxf(fmaxf(sacc[3][0], sacc[3][1]), sacc[3][2]);
    float tm = fmaxf(fmaxf(fmaxf(a0, a1), fmaxf(a2, a3)), fmaxf(a4, sacc[3][3]));
    tm = fmaxf(tm, __shfl_xor(tm, 16));
    tm = fmaxf(tm, __shfl_xor(tm, 32));
    // defer-max: rescale only when running max grew by > 8 (log2 units)
    if (!__all(tm <= mrow + 8.f)) {
      float mn = fmaxf(mrow, tm);
      float alpha = __builtin_amdgcn_exp2f(mrow - mn);
      mrow = mn;
      lrow *= alpha;
#pragma unroll
      for (int dj = 0; dj < 4; dj++)
#pragma unroll
        for (int r = 0; r < 4; r++) oacc[dj][r] *= alpha;
    }
    float rs = 0.f;
#pragma unroll
    for (int nj = 0; nj < 4; nj++)
#pragma unroll
      for (int r = 0; r < 4; r++) {
        float e = __builtin_amdgcn_exp2f(sacc[nj][r] - mrow);
        sacc[nj][r] = e;
        rs += e;
      }
    rs += __shfl_xor(rs, 16);
    rs += __shfl_xor(rs, 32);
    lrow += rs;
#pragma unroll
    for (int nj = 0; nj < 4; nj++) {
      u32x2 w2;
      w2[0] = cvt_pk_bf16(sacc[nj][0], sacc[nj][1]);
      w2[1] = cvt_pk_bf16(sacc[nj][2], sacc[nj][3]);
      *(u32x2*)&lPw[l15 * 64 + ((nj * 16 + quad * 4) ^ pswz)] = w2;
    }
    bf16x8 pf0 = *(const bf16x8*)&lPw[l15 * 64 + ((quad * 8) ^ pswz)];
    bf16x8 pf1 = *(const bf16x8*)&lPw[l15 * 64 + ((32 + quad * 8) ^ pswz)];
    __builtin_amdgcn_s_setprio(1);
#pragma unroll
    for (int dj = 0; dj < 4; dj++) {
      int ro = (dj * 16 + l15) * 32 + ((quad * 8) ^ swz);
      bf16x8 vf0 = *(const bf16x8*)&lV[cur][0][ro];
      bf16x8 vf1 = *(const bf16x8*)&lV[cur][1][ro];
      MFMA16(oacc[dj], vf0, pf0);
      MFMA16(oacc[dj], vf1, pf1);
    }
    __builtin_amdgcn_s_setprio(0);
  };

  // prologue
  stage(0, 0);
  WAITVM(0); BARRIER();

  int cur = 0;
  // ---- shared iterations: frags A and B, K fragments reused ----
  for (int t = 0; t < ntA; t++) {
    stage(t + 1, cur ^ 1);           // t+1 <= ntA < ntB: always valid
    f32x4 sA[4], sB[4];
    __builtin_amdgcn_s_setprio(1);
#pragma unroll
    for (int nj = 0; nj < 4; nj++) {
      int ro = (nj * 16 + l15) * 32 + ((quad * 8) ^ swz);
      bf16x8 kf0 = *(const bf16x8*)&lK[cur][0][ro];
      bf16x8 kf1 = *(const bf16x8*)&lK[cur][1][ro];
      sA[nj] = zero4;
      MFMA16(sA[nj], kf0, qfA0);
      MFMA16(sA[nj], kf1, qfA1);
      sB[nj] = zero4;
      MFMA16(sB[nj], kf0, qfB0);
      MFMA16(sB[nj], kf1, qfB1);
    }
    __builtin_amdgcn_s_setprio(0);
    smax_pv(sA, mA, lA, oA, cur, t * 64, qAg, (t * 64 + 63) > qAg);
    smax_pv(sB, mB, lB, oB, cur, t * 64, qBg, false);   // B diag unreachable in shared range
    WAITVM(0); BARRIER();
    cur ^= 1;
  }
  // ---- solo iterations: frag B only ----
  for (int t = ntA; t < ntB; t++) {
    if (t + 1 < ntB) stage(t + 1, cur ^ 1);
    f32x4 sB[4];
    __builtin_amdgcn_s_setprio(1);
#pragma unroll
    for (int nj = 0; nj < 4; nj++) {
      int ro = (nj * 16 + l15) * 32 + ((quad * 8) ^ swz);
      bf16x8 kf0 = *(const bf16x8*)&lK[cur][0][ro];
      bf16x8 kf1 = *(const bf16x8*)&lK[cur][1][ro];
      sB[nj] = zero4;
      MFMA16(sB[nj], kf0, qfB0);
      MFMA16(sB[nj], kf1, qfB1);
    }
    __builtin_amdgcn_s_setprio(0);
    smax_pv(sB, mB, lB, oB, cur, t * 64, qBg, (t * 64 + 63) > qBg);
    WAITVM(0); BARRIER();
    cur ^= 1;
  }

  // ---- epilogue ----
  auto wout = [&](f32x4 (&oacc)[4], float lrow, int qg) {
    float inv = __builtin_amdgcn_rcpf(lrow);
    size_t orow = ((size_t)b * DS + qg) * (DNH * DHD) + (size_t)h * DHD;
#pragma unroll
    for (int dj = 0; dj < 4; dj++) {
      u32x2 o2;
      o2[0] = cvt_pk_bf16(oacc[dj][0] * inv, oacc[dj][1] * inv);
      o2[1] = cvt_pk_bf16(oacc[dj][2] * inv, oacc[dj][3] * inv);
      *(u32x2*)&ctx[orow + dj * 16 + quad * 4] = o2;
    }
  };
  wout(oA, lA, qAg);
  wout(oB, lB, qBg);
}

extern "C" void kernel_launch(void* const* d_in, const int* in_sizes, int n_in,
                              void* d_out, int out_size, void* d_ws, size_t ws_size,
                              hipStream_t stream) {
  (void)in_sizes; (void)n_in; (void)out_size; (void)ws_size;
  const void* hs = d_in[0];
  const int* pos = (const int*)d_in[2];
  const void* wq = d_in[3];
  const void* wk = d_in[4];
  const void* wv = d_in[5];
  const void* wo = d_in[6];

  char* ws = (char*)d_ws;
  size_t off = 0;
  auto take = [&](size_t bytes) -> char* {
    char* p = ws + off;
    off += (bytes + 255) & ~(size_t)255;
    return p;
  };
  unsigned short* xb    = (unsigned short*)take((size_t)DM * DH * 2);
  unsigned short* wtqkv = (unsigned short*)take((size_t)DNQKV * DH * 2);
  unsigned short* wto   = (unsigned short*)take((size_t)DH * DH * 2);
  unsigned short* qws   = (unsigned short*)take((size_t)DB * DNH * DS * DHD * 2);
  unsigned short* kws   = (unsigned short*)take((size_t)DB * DKVH * DS * DHD * 2);
  unsigned short* vtws  = (unsigned short*)take((size_t)DB * DKVH * DS * DHD * 2);
  unsigned short* ctx   = (unsigned short*)take((size_t)DM * DNH * DHD * 2);

  prep<<<14336, 256, 0, stream>>>(hs, wq, wk, wv, wo, xb, wtqkv, wto);

  gemm_qkv<<<dim3(192), 512, 0, stream>>>(xb, wtqkv, pos, qws, kws, vtws);

  flash_attn<<<dim3(DB * DNH, 8), 512, 0, stream>>>(qws, kws, vtws, ctx);

  gemm_out<<<dim3(256), 512, 0, stream>>>(ctx, wto, (unsigned short*)d_out, (float*)d_out,
                                          (const unsigned short*)wq);
}